// Round 3
// baseline (1050.524 us; speedup 1.0000x reference)
//
#include <hip/hip_runtime.h>
#include <hip/hip_bf16.h>
#include <stdint.h>

typedef unsigned short u16;
typedef __attribute__((__vector_size__(16))) short s16x8;
typedef __attribute__((__vector_size__(16))) float f32x4;

#define N_ 16384
#define C_ 256

__device__ __forceinline__ float bf2f(u16 u) {
    union { uint32_t i; float f; } v; v.i = ((uint32_t)u) << 16; return v.f;
}
__device__ __forceinline__ u16 f2bf(float f) {
    union { uint32_t i; float f; } v; v.f = f;
    uint32_t u = v.i;
    return (u16)((u + 0x7FFFu + ((u >> 16) & 1u)) >> 16);
}

// async global->LDS, 16 B per lane. LDS dest = wave-uniform base + lane*16.
__device__ __forceinline__ void gl_lds16(const u16* g, u16* l) {
    __builtin_amdgcn_global_load_lds((__attribute__((address_space(1))) void*)g,
                                     (__attribute__((address_space(3))) void*)l,
                                     16, 0, 0);
}

__global__ __launch_bounds__(256) void zero_kernel(float* __restrict__ p, int n) {
    int i = blockIdx.x * 256 + threadIdx.x;
    if (i < n) p[i] = 0.f;
}

// ---------------------------------------------------------------------------
// K0: x fp32 [B][C][N] -> xT bf16 [B][N][C]
// ---------------------------------------------------------------------------
__global__ __launch_bounds__(256) void transpose_kernel(const float* __restrict__ x,
                                                        u16* __restrict__ xT) {
    __shared__ float T[64][65];
    int tid = threadIdx.x;
    int n0 = blockIdx.x * 64, c0 = blockIdx.y * 64, b = blockIdx.z;
    const float* xp = x + (size_t)b * C_ * N_;
    for (int it = 0; it < 16; it++) {
        int idx = it * 256 + tid;
        int c = idx >> 6, n = idx & 63;
        T[c][n] = xp[(size_t)(c0 + c) * N_ + n0 + n];
    }
    __syncthreads();
    u16* op = xT + (size_t)b * N_ * C_;
    for (int it = 0; it < 8; it++) {
        int idx = it * 256 + tid;
        int n = idx >> 5, c2 = (idx & 31) * 2;
        uint32_t lo = f2bf(T[c2][n]);
        uint32_t hi = f2bf(T[c2 + 1][n]);
        *(uint32_t*)&op[(size_t)(n0 + n) * C_ + c0 + c2] = lo | (hi << 16);
    }
}

// ---------------------------------------------------------------------------
// Kw: wq/wk/wv fp32 -> wb bf16 [3][512][256]
// ---------------------------------------------------------------------------
__global__ __launch_bounds__(256) void cvtw_kernel(const float* __restrict__ wq,
                                                   const float* __restrict__ wk,
                                                   const float* __restrict__ wv,
                                                   u16* __restrict__ wb) {
    int m = blockIdx.y;
    const float* s = m == 0 ? wq : (m == 1 ? wk : wv);
    int i = blockIdx.x * 256 + threadIdx.x;
    wb[(size_t)m * 131072 + i] = f2bf(s[i]);
}

// ===========================================================================
// Cooperative 2-phase staged GEMM mainloop (R1 structure, best measured).
// Swizzled Tile: [128 rows][64 halves], slot(row,c) = row*64 + ((c^(row&7))*8)
// ===========================================================================

#define STAGE2(WSRC, XSRC, LDW, KC, CUR) {                                         \
    int koff_ = (KC) * 64 + sc8;                                                   \
    _Pragma("unroll")                                                              \
    for (int i_ = 0; i_ < 4; i_++) {                                               \
        int row_ = (wid * 4 + i_) * 8 + srow;                                      \
        gl_lds16(&(WSRC)[(size_t)row_ * (LDW) + koff_], &SH[CUR][(wid * 4 + i_) * 512]);      \
        gl_lds16(&(XSRC)[(size_t)row_ * (LDW) + koff_], &SH[2 + (CUR)][(wid * 4 + i_) * 512]); \
    } }

// ---------------------------------------------------------------------------
// K1a (FUSED kv+ctx): per block = one head h, one 128-n slice.
// Weight tile rows 0..63 = wk[h*64..], rows 64..127 = wv[h*64..].
// GEMM 128x128x256 (identical structure to R1 kv), then LN (+exp/rowsum for
// k-half), then eK/V tiles -> LDS, 64x64x128 ctx contraction in-block,
// cross-wave reduce, atomicAdd to 8-way-sliced ctx8. NO eKb/vbb globals.
// grid (128 ntiles, 8 heads, B); block 256 (2x2 waves).
// ---------------------------------------------------------------------------
__global__ __launch_bounds__(256) void kvctx_kernel(
    const u16* __restrict__ xT, const u16* __restrict__ wb,
    const float* __restrict__ bk, const float* __restrict__ bv,
    const float* __restrict__ gk, const float* __restrict__ bek,
    const float* __restrict__ gv, const float* __restrict__ bev,
    float* __restrict__ ctx8, float* __restrict__ rs)
{
    // 4 x 17408 B slabs = 69632 B. Staging dbuf uses [w][0..8192) u16 per slab.
    // Epilogue aliases: ES=[SH+0,16KB), VS=[SH+16KB,32KB), CTXW[w]=slab w (f32).
    __shared__ u16 SH[4][8704];
    int tid = threadIdx.x;
    int lane = tid & 63, wid = tid >> 6;
    int quad = lane >> 4, l15 = lane & 15;
    int wm = wid >> 1, wn = wid & 1;
    int bx = blockIdx.x, h = blockIdx.y, b = blockIdx.z;
    int n0 = bx * 128;

    // wave wid stages W tile rows [wid*32, wid*32+32): wid<2 -> wk, else wv
    const u16* wsrcw = wb + (size_t)(1 + (wid >> 1)) * 131072
                          + ((size_t)h * 64 + (size_t)(wid & 1) * 32) * 256;
    const u16* xsrc = xT + ((size_t)b * N_ + n0) * 256;

    f32x4 acc[4][4];
#pragma unroll
    for (int i = 0; i < 4; i++)
#pragma unroll
        for (int j = 0; j < 4; j++) acc[i][j] = (f32x4){0.f, 0.f, 0.f, 0.f};

    int srow = lane >> 3;
    int sc8  = ((lane & 7) ^ srow) * 8;

    // fused stage: W rows via per-wave slab source, X rows as usual
#define STAGEF(KC, CUR) {                                                          \
    int koff_ = (KC) * 64 + sc8;                                                   \
    _Pragma("unroll")                                                              \
    for (int i_ = 0; i_ < 4; i_++) {                                               \
        int ri_ = i_ * 8 + srow;                                                   \
        gl_lds16(&wsrcw[(size_t)ri_ * 256 + koff_], &SH[CUR][(wid * 4 + i_) * 512]); \
        gl_lds16(&xsrc[(size_t)(wid * 32 + ri_) * 256 + koff_], &SH[2 + (CUR)][(wid * 4 + i_) * 512]); \
    } }

    STAGEF(0, 0);
    __syncthreads();
    for (int kc = 0; kc < 4; kc++) {
        int cur = kc & 1;
        if (kc < 3) STAGEF(kc + 1, cur ^ 1);
        const u16* Wb = &SH[cur][0];
        const u16* Xb = &SH[2 + cur][0];
#pragma unroll
        for (int ks = 0; ks < 2; ks++) {
            int cc = ks * 4 + quad;
            s16x8 af[4], bf[4];
#pragma unroll
            for (int f = 0; f < 4; f++) {
                int ar = wn * 64 + f * 16 + l15;   // A = x/n side
                int br = wm * 64 + f * 16 + l15;   // B = weight side (k half / v half)
                af[f] = *(const s16x8*)&Xb[ar * 64 + ((cc ^ (ar & 7)) * 8)];
                bf[f] = *(const s16x8*)&Wb[br * 64 + ((cc ^ (br & 7)) * 8)];
            }
#pragma unroll
            for (int i = 0; i < 4; i++)
#pragma unroll
                for (int j = 0; j < 4; j++)
                    acc[i][j] = __builtin_amdgcn_mfma_f32_16x16x32_bf16(af[i], bf[j], acc[i][j], 0, 0, 0);
        }
        if (kc < 3) __syncthreads();
    }

    // value(mf,nf,reg): n_local = wn*64+mf*16+quad*4+reg, dim-row = nf*16+l15
    // wm=0 -> k rows (kd), wm=1 -> v rows (vd), both of head h.
    const float* bptr  = wm ? bv  : bk;
    const float* gptr  = wm ? gv  : gk;
    const float* beptr = wm ? bev : bek;
    float bB_[4], gB[4], eB[4];
#pragma unroll
    for (int nf = 0; nf < 4; nf++) {
        int rl = nf * 16 + l15;
        bB_[nf] = bptr[h * 64 + rl];
        gB[nf]  = gptr[rl];
        eB[nf]  = beptr[rl];
    }
#pragma unroll
    for (int mf = 0; mf < 4; mf++)
#pragma unroll
        for (int nf = 0; nf < 4; nf++)
#pragma unroll
            for (int r = 0; r < 4; r++) acc[mf][nf][r] += bB_[nf];
    float sa[4][4], sb[4][4];
#pragma unroll
    for (int mf = 0; mf < 4; mf++)
#pragma unroll
        for (int r = 0; r < 4; r++) {
            float s = 0.f, s2 = 0.f;
#pragma unroll
            for (int nf = 0; nf < 4; nf++) { float v = acc[mf][nf][r]; s += v; s2 += v * v; }
            sa[mf][r] = s; sb[mf][r] = s2;
        }
#pragma unroll
    for (int msk = 1; msk <= 8; msk <<= 1)
#pragma unroll
        for (int mf = 0; mf < 4; mf++)
#pragma unroll
            for (int r = 0; r < 4; r++) {
                sa[mf][r] += __shfl_xor(sa[mf][r], msk);
                sb[mf][r] += __shfl_xor(sb[mf][r], msk);
            }
#pragma unroll
    for (int mf = 0; mf < 4; mf++)
#pragma unroll
        for (int r = 0; r < 4; r++) {
            float mu = sa[mf][r] * (1.f / 64.f);
            float rstd = rsqrtf(sb[mf][r] * (1.f / 64.f) - mu * mu + 1e-5f);
#pragma unroll
            for (int nf = 0; nf < 4; nf++)
                acc[mf][nf][r] = (acc[mf][nf][r] - mu) * rstd * gB[nf] + eB[nf];
        }
    if (wm == 0) {
#pragma unroll
        for (int mf = 0; mf < 4; mf++)
#pragma unroll
            for (int nf = 0; nf < 4; nf++)
#pragma unroll
                for (int r = 0; r < 4; r++) acc[mf][nf][r] = __expf(acc[mf][nf][r]);
#pragma unroll
        for (int nf = 0; nf < 4; nf++) {
            float s = 0.f;
#pragma unroll
            for (int mf = 0; mf < 4; mf++)
#pragma unroll
                for (int r = 0; r < 4; r++) s += acc[mf][nf][r];
            s += __shfl_xor(s, 16); s += __shfl_xor(s, 32);
            if (quad == 0)
                atomicAdd(&rs[(size_t)b * 512 + h * 64 + nf * 16 + l15], s);
        }
    }

    // --- ctx contraction in-block ---
    __syncthreads();   // all waves done reading staging LDS
    u16* ES = (u16*)SH;          // eK tile [64 kd][128 n], swizzled
    u16* VS = ES + 8192;         // v  tile [64 vd][128 n], swizzled
    {
        u16* st = wm ? VS : ES;
#pragma unroll
        for (int mf = 0; mf < 4; mf++)
#pragma unroll
            for (int nf = 0; nf < 4; nf++) {
                int rh = nf * 16 + l15;
                int ln = wn * 64 + mf * 16 + quad * 4;
                int c  = ln >> 3;
                int off = rh * 128 + ((c ^ (rh & 15)) * 8) + (ln & 7);
                uint64_t w0 = (uint64_t)f2bf(acc[mf][nf][0]) | ((uint64_t)f2bf(acc[mf][nf][1]) << 16) |
                              ((uint64_t)f2bf(acc[mf][nf][2]) << 32) | ((uint64_t)f2bf(acc[mf][nf][3]) << 48);
                *(uint64_t*)&st[off] = w0;
            }
    }
    __syncthreads();
    // wave wid contracts n-chunks cc = wid*4+quad (32 n per wave)
    f32x4 cacc[4][4];
#pragma unroll
    for (int i = 0; i < 4; i++)
#pragma unroll
        for (int j = 0; j < 4; j++) cacc[i][j] = (f32x4){0.f, 0.f, 0.f, 0.f};
    {
        int cc = wid * 4 + quad;
        s16x8 caf[4], cbf[4];
#pragma unroll
        for (int f = 0; f < 4; f++) {
            int off = (f * 16 + l15) * 128 + ((cc ^ l15) * 8);
            caf[f] = *(const s16x8*)&ES[off];
            cbf[f] = *(const s16x8*)&VS[off];
        }
#pragma unroll
        for (int i = 0; i < 4; i++)
#pragma unroll
            for (int j = 0; j < 4; j++)
                cacc[i][j] = __builtin_amdgcn_mfma_f32_16x16x32_bf16(caf[i], cbf[j], cacc[i][j], 0, 0, 0);
    }
    __syncthreads();   // done reading ES/VS; slabs become CTXW
    // per-wave partial ctx: CTXW[wid][vd*68 + kd] (pad 68 -> bank spread, 16B align)
    {
        float* CTXW = (float*)((char*)SH + (size_t)wid * 17408);
#pragma unroll
        for (int mf = 0; mf < 4; mf++)
#pragma unroll
            for (int nf = 0; nf < 4; nf++) {
                int kd = mf * 16 + quad * 4, vd = nf * 16 + l15;
                *(f32x4*)&CTXW[vd * 68 + kd] = cacc[mf][nf];
            }
    }
    __syncthreads();
    // reduce 4 wave slabs, atomicAdd to ctx8 slice (bx&7): [s][b][h][vd][kd]
    {
        int vd = tid >> 2, kd0 = (tid & 3) * 16;
        const float* C0 = (const float*)((char*)SH);
        const float* C1 = (const float*)((char*)SH + 17408);
        const float* C2 = (const float*)((char*)SH + 34816);
        const float* C3 = (const float*)((char*)SH + 52224);
        float* gctx = ctx8 + ((((size_t)(bx & 7) * 4 + b) * 8 + h) * 64 + vd) * 64 + kd0;
#pragma unroll
        for (int j4 = 0; j4 < 4; j4++) {
            int o = vd * 68 + kd0 + j4 * 4;
            f32x4 s = *(const f32x4*)&C0[o];
            s += *(const f32x4*)&C1[o];
            s += *(const f32x4*)&C2[o];
            s += *(const f32x4*)&C3[o];
#pragma unroll
            for (int r = 0; r < 4; r++) atomicAdd(&gctx[j4 * 4 + r], s[r]);
        }
    }
#undef STAGEF
}

// ---------------------------------------------------------------------------
// K1b: q projection + bias + LN + softmax(dim) -> qT[b][n][512]
// grid (128 ntiles, 4 pairs, B); block 256. (R1 structure)
// ---------------------------------------------------------------------------
__global__ __launch_bounds__(256) void q_kernel(
    const u16* __restrict__ xT, const u16* __restrict__ wb,
    const float* __restrict__ bq, const float* __restrict__ gq, const float* __restrict__ beq,
    u16* __restrict__ qT)
{
    __shared__ u16 SH[4][8192];
    int tid = threadIdx.x;
    int lane = tid & 63, wid = tid >> 6;
    int quad = lane >> 4, l15 = lane & 15;
    int wm = wid >> 1, wn = wid & 1;
    int bx = blockIdx.x, pair = blockIdx.y, b = blockIdx.z;
    int r0 = pair * 128;
    int n0 = bx * 128;

    const u16* wsrc = wb + (size_t)r0 * 256;
    const u16* xsrc = xT + ((size_t)b * N_ + n0) * 256;

    f32x4 acc[4][4];
#pragma unroll
    for (int i = 0; i < 4; i++)
#pragma unroll
        for (int j = 0; j < 4; j++) acc[i][j] = (f32x4){0.f, 0.f, 0.f, 0.f};

    int srow = lane >> 3;
    int sc8  = ((lane & 7) ^ srow) * 8;

    STAGE2(wsrc, xsrc, 256, 0, 0);
    __syncthreads();
    for (int kc = 0; kc < 4; kc++) {
        int cur = kc & 1;
        if (kc < 3) STAGE2(wsrc, xsrc, 256, kc + 1, cur ^ 1);
        const u16* Wb = &SH[cur][0];
        const u16* Xb = &SH[2 + cur][0];
#pragma unroll
        for (int ks = 0; ks < 2; ks++) {
            int cc = ks * 4 + quad;
            s16x8 af[4], bf[4];
#pragma unroll
            for (int f = 0; f < 4; f++) {
                int ar = wm * 64 + f * 16 + l15;   // A = weight side
                int br = wn * 64 + f * 16 + l15;   // B = x/n side
                af[f] = *(const s16x8*)&Wb[ar * 64 + ((cc ^ (ar & 7)) * 8)];
                bf[f] = *(const s16x8*)&Xb[br * 64 + ((cc ^ (br & 7)) * 8)];
            }
#pragma unroll
            for (int i = 0; i < 4; i++)
#pragma unroll
                for (int j = 0; j < 4; j++)
                    acc[i][j] = __builtin_amdgcn_mfma_f32_16x16x32_bf16(af[i], bf[j], acc[i][j], 0, 0, 0);
        }
        if (kc < 3) __syncthreads();
    }

    // value(mf,nf,reg): row rl = mf*16+quad*4+reg (in head), col n = wn*64+nf*16+l15
    float bA[4][4], gA[4][4], eA[4][4];
#pragma unroll
    for (int mf = 0; mf < 4; mf++)
#pragma unroll
        for (int r = 0; r < 4; r++) {
            int rl = mf * 16 + quad * 4 + r;
            bA[mf][r] = bq[r0 + wm * 64 + rl];
            gA[mf][r] = gq[rl];
            eA[mf][r] = beq[rl];
        }
#pragma unroll
    for (int mf = 0; mf < 4; mf++)
#pragma unroll
        for (int nf = 0; nf < 4; nf++)
#pragma unroll
            for (int r = 0; r < 4; r++) acc[mf][nf][r] += bA[mf][r];
#pragma unroll
    for (int nf = 0; nf < 4; nf++) {
        float s = 0.f, s2 = 0.f;
#pragma unroll
        for (int mf = 0; mf < 4; mf++)
#pragma unroll
            for (int r = 0; r < 4; r++) { float v = acc[mf][nf][r]; s += v; s2 += v * v; }
        s  += __shfl_xor(s, 16);  s  += __shfl_xor(s, 32);
        s2 += __shfl_xor(s2, 16); s2 += __shfl_xor(s2, 32);
        float mu = s * (1.f / 64.f);
        float rstd = rsqrtf(s2 * (1.f / 64.f) - mu * mu + 1e-5f);
#pragma unroll
        for (int mf = 0; mf < 4; mf++)
#pragma unroll
            for (int r = 0; r < 4; r++)
                acc[mf][nf][r] = (acc[mf][nf][r] - mu) * rstd * gA[mf][r] + eA[mf][r];
    }
    const float s_q = 0.35355339059327373f;
#pragma unroll
    for (int nf = 0; nf < 4; nf++) {
        float m = -1e30f;
#pragma unroll
        for (int mf = 0; mf < 4; mf++)
#pragma unroll
            for (int r = 0; r < 4; r++) { acc[mf][nf][r] *= s_q; m = fmaxf(m, acc[mf][nf][r]); }
        m = fmaxf(m, __shfl_xor(m, 16)); m = fmaxf(m, __shfl_xor(m, 32));
        float d = 0.f;
#pragma unroll
        for (int mf = 0; mf < 4; mf++)
#pragma unroll
            for (int r = 0; r < 4; r++) { float e = __expf(acc[mf][nf][r] - m); acc[mf][nf][r] = e; d += e; }
        d += __shfl_xor(d, 16); d += __shfl_xor(d, 32);
        float inv = 1.f / d;
#pragma unroll
        for (int mf = 0; mf < 4; mf++)
#pragma unroll
            for (int r = 0; r < 4; r++) acc[mf][nf][r] *= inv;
    }
    // store via LDS staging: region wn=0 -> SH[0] (n 0..63), wn=1 -> SH[2].
    u16* st = (wn == 0) ? &SH[0][0] : &SH[2][0];
#pragma unroll
    for (int mf = 0; mf < 4; mf++)
#pragma unroll
        for (int nf = 0; nf < 4; nf++) {
            int nl = nf * 16 + l15;
            int gl = wm * 64 + mf * 16 + quad * 4;
            int c  = gl >> 3;
            int off = nl * 128 + ((c ^ (nl & 15)) * 8) + (gl & 7);
            uint64_t w0 = (uint64_t)f2bf(acc[mf][nf][0]) | ((uint64_t)f2bf(acc[mf][nf][1]) << 16) |
                          ((uint64_t)f2bf(acc[mf][nf][2]) << 32) | ((uint64_t)f2bf(acc[mf][nf][3]) << 48);
            *(uint64_t*)&st[off] = w0;
        }
    __syncthreads();
    {
        u16* qp = qT + (size_t)b * N_ * 512;
#pragma unroll
        for (int i = 0; i < 8; i++) {
            int idx = i * 256 + tid;
            int n = idx >> 4, cp = idx & 15;
            const u16* src = (n < 64) ? &SH[0][0] : &SH[2][0];
            int nl = n & 63;
            s16x8 v = *(const s16x8*)&src[nl * 128 + ((cp ^ (nl & 15)) * 8)];
            *(s16x8*)&qp[(size_t)(n0 + n) * 512 + r0 + cp * 8] = v;
        }
    }
}

// ---------------------------------------------------------------------------
// K3: Weff[b][c][h*64+kd] = sum_vd wo[c][h*64+vd] * (ctx/rs); ctx = sum of 8
// slices, slice layout [s][b][h][vd][kd].
// ---------------------------------------------------------------------------
__global__ __launch_bounds__(256) void weff_kernel(
    const float* __restrict__ ctx8, const float* __restrict__ rs,
    const float* __restrict__ wo, u16* __restrict__ Weffb)
{
    __shared__ float CT[16][65];
    int tid = threadIdx.x;
    int h = blockIdx.x, b = blockIdx.y, kc = blockIdx.z;
    for (int i = tid; i < 1024; i += 256) {
        int kdl = i >> 6, vd = i & 63;
        int kd = kc * 16 + kdl;
        float s = 0.f;
#pragma unroll
        for (int sl = 0; sl < 8; sl++)
            s += ctx8[((((size_t)sl * 4 + b) * 8 + h) * 64 + vd) * 64 + kd];
        CT[kdl][vd] = s / rs[(size_t)b * 512 + h * 64 + kd];
    }
    __syncthreads();
    int c = tid;
    float wrow[64];
    const float4* wp = (const float4*)(wo + (size_t)c * 512 + h * 64);
#pragma unroll
    for (int i = 0; i < 16; i++) { float4 t = wp[i]; wrow[i*4] = t.x; wrow[i*4+1] = t.y; wrow[i*4+2] = t.z; wrow[i*4+3] = t.w; }
    for (int kdl = 0; kdl < 16; kdl++) {
        float s = 0.f;
#pragma unroll
        for (int vd = 0; vd < 64; vd++) s += wrow[vd] * CT[kdl][vd];
        Weffb[((size_t)b * 256 + c) * 512 + h * 64 + kc * 16 + kdl] = f2bf(s);
    }
}

// ---------------------------------------------------------------------------
// K4: out[c][n] = sum_r Weff[c][r] qT[n][r] + bo[c]   (MFMA, K=512, pipelined)
// ---------------------------------------------------------------------------
__global__ __launch_bounds__(256) void out_kernel(
    const u16* __restrict__ Weffb, const u16* __restrict__ qT,
    const float* __restrict__ bo, float* __restrict__ out)
{
    __shared__ u16 SH[4][8192];
    int tid = threadIdx.x;
    int lane = tid & 63, wid = tid >> 6;
    int quad = lane >> 4, l15 = lane & 15;
    int wm = wid >> 1, wn = wid & 1;
    int n0 = blockIdx.x * 128, c0 = blockIdx.y * 128, b = blockIdx.z;
    const u16* asrc = Weffb + ((size_t)b * 256 + c0) * 512;
    const u16* bsrc = qT + ((size_t)b * N_ + n0) * 512;

    f32x4 acc[4][4];
#pragma unroll
    for (int i = 0; i < 4; i++)
#pragma unroll
        for (int j = 0; j < 4; j++) acc[i][j] = (f32x4){0.f, 0.f, 0.f, 0.f};

    int srow = lane >> 3;
    int sc8  = ((lane & 7) ^ srow) * 8;

    STAGE2(asrc, bsrc, 512, 0, 0);
    __syncthreads();
    for (int kc = 0; kc < 8; kc++) {
        int cur = kc & 1;
        if (kc < 7) STAGE2(asrc, bsrc, 512, kc + 1, cur ^ 1);
        const u16* Wb = &SH[cur][0];
        const u16* Xb = &SH[2 + cur][0];
#pragma unroll
        for (int ks = 0; ks < 2; ks++) {
            int cc = ks * 4 + quad;
            s16x8 af[4], bf[4];
#pragma unroll
            for (int f = 0; f < 4; f++) {
                int ar = wm * 64 + f * 16 + l15;
                int br = wn * 64 + f * 16 + l15;
                af[f] = *(const s16x8*)&Wb[ar * 64 + ((cc ^ (ar & 7)) * 8)];
                bf[f] = *(const s16x8*)&Xb[br * 64 + ((cc ^ (br & 7)) * 8)];
            }
#pragma unroll
            for (int i = 0; i < 4; i++)
#pragma unroll
                for (int j = 0; j < 4; j++)
                    acc[i][j] = __builtin_amdgcn_mfma_f32_16x16x32_bf16(af[i], bf[j], acc[i][j], 0, 0, 0);
        }
        if (kc < 7) __syncthreads();
    }
#pragma unroll
    for (int mf = 0; mf < 4; mf++)
#pragma unroll
        for (int r = 0; r < 4; r++) {
            int c = c0 + wm * 64 + mf * 16 + quad * 4 + r;
            float bov = bo[c];
#pragma unroll
            for (int nf = 0; nf < 4; nf++)
                out[((size_t)b * 256 + c) * N_ + n0 + wn * 64 + nf * 16 + l15] = acc[mf][nf][r] + bov;
        }
}

extern "C" void kernel_launch(void* const* d_in, const int* in_sizes, int n_in,
                              void* d_out, int out_size, void* d_ws, size_t ws_size,
                              hipStream_t stream) {
    const float* x   = (const float*)d_in[0];
    const float* wq  = (const float*)d_in[1];
    const float* bq  = (const float*)d_in[2];
    const float* wk  = (const float*)d_in[3];
    const float* bk  = (const float*)d_in[4];
    const float* wv  = (const float*)d_in[5];
    const float* bv  = (const float*)d_in[6];
    const float* wo  = (const float*)d_in[7];
    const float* bo  = (const float*)d_in[8];
    const float* gq  = (const float*)d_in[9];
    const float* beq = (const float*)d_in[10];
    const float* gk  = (const float*)d_in[11];
    const float* bek = (const float*)d_in[12];
    const float* gv  = (const float*)d_in[13];
    const float* bev = (const float*)d_in[14];
    float* out = (float*)d_out;

    char* ws = (char*)d_ws;
    // xT   [0, 33554432)            bf16 [B][N][C]
    // wb   [33554432, 34340864)     bf16 [3][512][256]
    // qT   [34340864, 101449728)    bf16 [B][N][512]
    // ctx8 [101449728, 105644032)   fp32 [8][B][8][64][64]  (8 slices)
    // rs   [169082880, 169091072)   fp32 [B][512]
    // Weff [169091072, 170139648)   bf16 [B][256][512]
    u16* xT      = (u16*)(ws);
    u16* wb      = (u16*)(ws + 33554432ULL);
    u16* qT      = (u16*)(ws + 34340864ULL);
    float* ctx8  = (float*)(ws + 101449728ULL);
    float* rs    = (float*)(ws + 169082880ULL);
    u16* Weffb   = (u16*)(ws + 169091072ULL);

    cvtw_kernel<<<dim3(512, 3), 256, 0, stream>>>(wq, wk, wv, wb);
    transpose_kernel<<<dim3(256, 4, 4), 256, 0, stream>>>(x, xT);
    zero_kernel<<<dim3(4096), 256, 0, stream>>>(ctx8, 1048576);
    zero_kernel<<<dim3(8), 256, 0, stream>>>(rs, 2048);

    kvctx_kernel<<<dim3(128, 8, 4), 256, 0, stream>>>(
        xT, wb, bk, bv, gk, bek, gv, bev, ctx8, rs);

    q_kernel<<<dim3(128, 4, 4), 256, 0, stream>>>(xT, wb, bq, gq, beq, qT);

    weff_kernel<<<dim3(8, 4, 4), 256, 0, stream>>>(ctx8, rs, wo, Weffb);

    out_kernel<<<dim3(128, 2, 4), 256, 0, stream>>>(Weffb, qT, bo, out);
}

// Round 4
// 342.213 us; speedup vs baseline: 3.0698x; 3.0698x over previous
//
#include <hip/hip_runtime.h>
#include <hip/hip_bf16.h>
#include <stdint.h>

typedef unsigned short u16;
typedef __attribute__((__vector_size__(16))) short s16x8;
typedef __attribute__((__vector_size__(16))) float f32x4;

#define N_ 16384
#define C_ 256

__device__ __forceinline__ float bf2f(u16 u) {
    union { uint32_t i; float f; } v; v.i = ((uint32_t)u) << 16; return v.f;
}
__device__ __forceinline__ u16 f2bf(float f) {
    union { uint32_t i; float f; } v; v.f = f;
    uint32_t u = v.i;
    return (u16)((u + 0x7FFFu + ((u >> 16) & 1u)) >> 16);
}

// async global->LDS, 16 B per lane. LDS dest = wave-uniform base + lane*16.
__device__ __forceinline__ void gl_lds16(const u16* g, u16* l) {
    __builtin_amdgcn_global_load_lds((__attribute__((address_space(1))) void*)g,
                                     (__attribute__((address_space(3))) void*)l,
                                     16, 0, 0);
}

__global__ __launch_bounds__(256) void zero_kernel(float* __restrict__ p, int n) {
    int i = blockIdx.x * 256 + threadIdx.x;
    if (i < n) p[i] = 0.f;
}

// ---------------------------------------------------------------------------
// K0: x fp32 [B][C][N] -> xT bf16 [B][N][C]
// ---------------------------------------------------------------------------
__global__ __launch_bounds__(256) void transpose_kernel(const float* __restrict__ x,
                                                        u16* __restrict__ xT) {
    __shared__ float T[64][65];
    int tid = threadIdx.x;
    int n0 = blockIdx.x * 64, c0 = blockIdx.y * 64, b = blockIdx.z;
    const float* xp = x + (size_t)b * C_ * N_;
    for (int it = 0; it < 16; it++) {
        int idx = it * 256 + tid;
        int c = idx >> 6, n = idx & 63;
        T[c][n] = xp[(size_t)(c0 + c) * N_ + n0 + n];
    }
    __syncthreads();
    u16* op = xT + (size_t)b * N_ * C_;
    for (int it = 0; it < 8; it++) {
        int idx = it * 256 + tid;
        int n = idx >> 5, c2 = (idx & 31) * 2;
        uint32_t lo = f2bf(T[c2][n]);
        uint32_t hi = f2bf(T[c2 + 1][n]);
        *(uint32_t*)&op[(size_t)(n0 + n) * C_ + c0 + c2] = lo | (hi << 16);
    }
}

// ---------------------------------------------------------------------------
// Kw: wq/wk/wv fp32 -> wb bf16 [3][512][256]
// ---------------------------------------------------------------------------
__global__ __launch_bounds__(256) void cvtw_kernel(const float* __restrict__ wq,
                                                   const float* __restrict__ wk,
                                                   const float* __restrict__ wv,
                                                   u16* __restrict__ wb) {
    int m = blockIdx.y;
    const float* s = m == 0 ? wq : (m == 1 ? wk : wv);
    int i = blockIdx.x * 256 + threadIdx.x;
    wb[(size_t)m * 131072 + i] = f2bf(s[i]);
}

// ===========================================================================
// Cooperative 2-phase staged GEMM mainloop (R1 structure, best measured).
// Swizzled Tile: [128 rows][64 halves], slot(row,c) = row*64 + ((c^(row&7))*8)
// ===========================================================================

#define STAGE2(WSRC, XSRC, LDW, KC, CUR) {                                         \
    int koff_ = (KC) * 64 + sc8;                                                   \
    _Pragma("unroll")                                                              \
    for (int i_ = 0; i_ < 4; i_++) {                                               \
        int row_ = (wid * 4 + i_) * 8 + srow;                                      \
        gl_lds16(&(WSRC)[(size_t)row_ * (LDW) + koff_], &SH[CUR][(wid * 4 + i_) * 512]);      \
        gl_lds16(&(XSRC)[(size_t)row_ * (LDW) + koff_], &SH[2 + (CUR)][(wid * 4 + i_) * 512]); \
    } }

// ---------------------------------------------------------------------------
// K1a (FUSED kv+ctx, no atomics): per block = one head h, 8 n-subtiles of 128.
// Per subtile: 128x128x256 GEMM (rows 0..63 = wk[h], 64..127 = wv[h]),
// LN (+exp for k-half), eK/V -> LDS (slab pair = dbuf parity complement),
// ctx MFMA accumulating into persistent cacc registers. Block end: cross-wave
// LDS reduce, ONE non-atomic 16KB partial write -> ctxp[b][h][ns][64][64].
// rs rowsums accumulate in regs, one atomicAdd per lane at block end.
// grid (16 ns, 8 heads, B); block 256 (2x2 waves).
// ---------------------------------------------------------------------------
__global__ __launch_bounds__(256) void kvctx_kernel(
    const u16* __restrict__ xT, const u16* __restrict__ wb,
    const float* __restrict__ bk, const float* __restrict__ bv,
    const float* __restrict__ gk, const float* __restrict__ bek,
    const float* __restrict__ gv, const float* __restrict__ bev,
    float* __restrict__ ctxp, float* __restrict__ rs)
{
    // 4 slabs x 17408 B = 69632 B. Staging uses [s][0..8192) u16.
    // Subtile-t epilogue: ES = slab (t&1), VS = slab 2+(t&1)  (pair not holding
    // the kc=3 data, whose last read was barrier-separated).
    // Block-end: CTXW[w] = slab w as f32[64*68] (17408 B exactly).
    __shared__ u16 SH[4][8704];
    int tid = threadIdx.x;
    int lane = tid & 63, wid = tid >> 6;
    int quad = lane >> 4, l15 = lane & 15;
    int wm = wid >> 1, wn = wid & 1;
    int ns = blockIdx.x, h = blockIdx.y, b = blockIdx.z;

    // wave wid stages W tile rows [wid*32, wid*32+32): wid<2 -> wk, else wv
    const u16* wsrcw = wb + (size_t)(1 + (wid >> 1)) * 131072
                          + ((size_t)h * 64 + (size_t)(wid & 1) * 32) * 256;

    int srow = lane >> 3;
    int sc8  = ((lane & 7) ^ srow) * 8;

#define STAGEF(XP, KC, CUR) {                                                      \
    int koff_ = (KC) * 64 + sc8;                                                   \
    _Pragma("unroll")                                                              \
    for (int i_ = 0; i_ < 4; i_++) {                                               \
        int ri_ = i_ * 8 + srow;                                                   \
        gl_lds16(&wsrcw[(size_t)ri_ * 256 + koff_], &SH[CUR][(wid * 4 + i_) * 512]); \
        gl_lds16(&(XP)[(size_t)(wid * 32 + ri_) * 256 + koff_], &SH[2 + (CUR)][(wid * 4 + i_) * 512]); \
    } }

    const float* bptr  = wm ? bv  : bk;
    const float* gptr  = wm ? gv  : gk;
    const float* beptr = wm ? bev : bek;
    float bB_[4], gB[4], eB[4];
#pragma unroll
    for (int nf = 0; nf < 4; nf++) {
        int rl = nf * 16 + l15;
        bB_[nf] = bptr[h * 64 + rl];
        gB[nf]  = gptr[rl];
        eB[nf]  = beptr[rl];
    }

    f32x4 cacc[4][4];
#pragma unroll
    for (int i = 0; i < 4; i++)
#pragma unroll
        for (int j = 0; j < 4; j++) cacc[i][j] = (f32x4){0.f, 0.f, 0.f, 0.f};
    float rs_acc[4] = {0.f, 0.f, 0.f, 0.f};

    {
        const u16* x0 = xT + ((size_t)b * N_ + (size_t)(ns * 8) * 128) * 256;
        STAGEF(x0, 0, 0);
    }
    __syncthreads();

    for (int t = 0; t < 8; t++) {
        const u16* xcur = xT + ((size_t)b * N_ + (size_t)(ns * 8 + t) * 128) * 256;

        f32x4 acc[4][4];
#pragma unroll
        for (int i = 0; i < 4; i++)
#pragma unroll
            for (int j = 0; j < 4; j++) acc[i][j] = (f32x4){0.f, 0.f, 0.f, 0.f};

        for (int kc = 0; kc < 4; kc++) {
            int cur = (kc + t) & 1;
            if (kc < 3) STAGEF(xcur, kc + 1, cur ^ 1);
            const u16* Wb = &SH[cur][0];
            const u16* Xb = &SH[2 + cur][0];
#pragma unroll
            for (int ks = 0; ks < 2; ks++) {
                int cc = ks * 4 + quad;
                s16x8 af[4], bf[4];
#pragma unroll
                for (int f = 0; f < 4; f++) {
                    int ar = wn * 64 + f * 16 + l15;   // A = x/n side
                    int br = wm * 64 + f * 16 + l15;   // B = weight side (k/v half)
                    af[f] = *(const s16x8*)&Xb[ar * 64 + ((cc ^ (ar & 7)) * 8)];
                    bf[f] = *(const s16x8*)&Wb[br * 64 + ((cc ^ (br & 7)) * 8)];
                }
#pragma unroll
                for (int i = 0; i < 4; i++)
#pragma unroll
                    for (int j = 0; j < 4; j++)
                        acc[i][j] = __builtin_amdgcn_mfma_f32_16x16x32_bf16(af[i], bf[j], acc[i][j], 0, 0, 0);
            }
            if (kc < 3) __syncthreads();
        }

        // --- subtile epilogue (registers only): bias + LN (+ exp/rowsum k-half)
#pragma unroll
        for (int mf = 0; mf < 4; mf++)
#pragma unroll
            for (int nf = 0; nf < 4; nf++)
#pragma unroll
                for (int r = 0; r < 4; r++) acc[mf][nf][r] += bB_[nf];
        float sa[4][4], sb[4][4];
#pragma unroll
        for (int mf = 0; mf < 4; mf++)
#pragma unroll
            for (int r = 0; r < 4; r++) {
                float s = 0.f, s2 = 0.f;
#pragma unroll
                for (int nf = 0; nf < 4; nf++) { float v = acc[mf][nf][r]; s += v; s2 += v * v; }
                sa[mf][r] = s; sb[mf][r] = s2;
            }
#pragma unroll
        for (int msk = 1; msk <= 8; msk <<= 1)
#pragma unroll
            for (int mf = 0; mf < 4; mf++)
#pragma unroll
                for (int r = 0; r < 4; r++) {
                    sa[mf][r] += __shfl_xor(sa[mf][r], msk);
                    sb[mf][r] += __shfl_xor(sb[mf][r], msk);
                }
#pragma unroll
        for (int mf = 0; mf < 4; mf++)
#pragma unroll
            for (int r = 0; r < 4; r++) {
                float mu = sa[mf][r] * (1.f / 64.f);
                float rstd = rsqrtf(sb[mf][r] * (1.f / 64.f) - mu * mu + 1e-5f);
#pragma unroll
                for (int nf = 0; nf < 4; nf++)
                    acc[mf][nf][r] = (acc[mf][nf][r] - mu) * rstd * gB[nf] + eB[nf];
            }
        if (wm == 0) {
#pragma unroll
            for (int mf = 0; mf < 4; mf++)
#pragma unroll
                for (int nf = 0; nf < 4; nf++)
#pragma unroll
                    for (int r = 0; r < 4; r++) acc[mf][nf][r] = __expf(acc[mf][nf][r]);
#pragma unroll
            for (int nf = 0; nf < 4; nf++) {
                float s = 0.f;
#pragma unroll
                for (int mf = 0; mf < 4; mf++)
#pragma unroll
                    for (int r = 0; r < 4; r++) s += acc[mf][nf][r];
                s += __shfl_xor(s, 16); s += __shfl_xor(s, 32);
                rs_acc[nf] += s;
            }
        }

        // --- eK/V -> LDS slab pair (t&1): last read at kc2 compute, barrier-safe
        int esb = t & 1;
        u16* ES = &SH[esb][0];
        u16* VS = &SH[2 + esb][0];
        {
            u16* st = wm ? VS : ES;
#pragma unroll
            for (int mf = 0; mf < 4; mf++)
#pragma unroll
                for (int nf = 0; nf < 4; nf++) {
                    int rh = nf * 16 + l15;
                    int ln = wn * 64 + mf * 16 + quad * 4;
                    int c  = ln >> 3;
                    int off = rh * 128 + ((c ^ (rh & 15)) * 8) + (ln & 7);
                    uint64_t w0 = (uint64_t)f2bf(acc[mf][nf][0]) | ((uint64_t)f2bf(acc[mf][nf][1]) << 16) |
                                  ((uint64_t)f2bf(acc[mf][nf][2]) << 32) | ((uint64_t)f2bf(acc[mf][nf][3]) << 48);
                    *(uint64_t*)&st[off] = w0;
                }
        }
        __syncthreads();   // sync(A): ES/VS visible; kc3 readers done -> prefetch safe

        if (t < 7) {
            const u16* xnext = xT + ((size_t)b * N_ + (size_t)(ns * 8 + t + 1) * 128) * 256;
            STAGEF(xnext, 0, (t + 1) & 1);
        }
        // ctx contraction: wave wid handles n-chunks cc = wid*4+quad
        {
            int cc = wid * 4 + quad;
            s16x8 caf[4], cbf[4];
#pragma unroll
            for (int f = 0; f < 4; f++) {
                int off = (f * 16 + l15) * 128 + ((cc ^ l15) * 8);
                caf[f] = *(const s16x8*)&ES[off];
                cbf[f] = *(const s16x8*)&VS[off];
            }
#pragma unroll
            for (int i = 0; i < 4; i++)
#pragma unroll
                for (int j = 0; j < 4; j++)
                    cacc[i][j] = __builtin_amdgcn_mfma_f32_16x16x32_bf16(caf[i], cbf[j], cacc[i][j], 0, 0, 0);
        }
        __syncthreads();   // sync(B): prefetch drained; ES/VS reads done
    }

    // --- block end: rs atomics (tiny) + cross-wave ctx reduce + partial write
    if (wm == 0 && quad == 0) {
#pragma unroll
        for (int nf = 0; nf < 4; nf++)
            atomicAdd(&rs[(size_t)b * 512 + h * 64 + nf * 16 + l15], rs_acc[nf]);
    }
    {
        float* CTXW = (float*)((char*)SH + (size_t)wid * 17408);
#pragma unroll
        for (int mf = 0; mf < 4; mf++)
#pragma unroll
            for (int nf = 0; nf < 4; nf++) {
                int kd = mf * 16 + quad * 4, vd = nf * 16 + l15;
                *(f32x4*)&CTXW[vd * 68 + kd] = cacc[mf][nf];
            }
    }
    __syncthreads();
    {
        int vd = tid >> 2, kd0 = (tid & 3) * 16;
        const float* C0 = (const float*)((char*)SH);
        const float* C1 = (const float*)((char*)SH + 17408);
        const float* C2 = (const float*)((char*)SH + 34816);
        const float* C3 = (const float*)((char*)SH + 52224);
        float* gp = ctxp + (((size_t)(b * 8 + h) * 16 + ns) * 4096) + vd * 64 + kd0;
#pragma unroll
        for (int j4 = 0; j4 < 4; j4++) {
            int o = vd * 68 + kd0 + j4 * 4;
            f32x4 s = *(const f32x4*)&C0[o];
            s += *(const f32x4*)&C1[o];
            s += *(const f32x4*)&C2[o];
            s += *(const f32x4*)&C3[o];
            *(f32x4*)&gp[j4 * 4] = s;
        }
    }
#undef STAGEF
}

// ---------------------------------------------------------------------------
// K1b: q projection + bias + LN + softmax(dim) -> qT[b][n][512]
// grid (128 ntiles, 4 pairs, B); block 256. (R1 structure)
// ---------------------------------------------------------------------------
__global__ __launch_bounds__(256) void q_kernel(
    const u16* __restrict__ xT, const u16* __restrict__ wb,
    const float* __restrict__ bq, const float* __restrict__ gq, const float* __restrict__ beq,
    u16* __restrict__ qT)
{
    __shared__ u16 SH[4][8192];
    int tid = threadIdx.x;
    int lane = tid & 63, wid = tid >> 6;
    int quad = lane >> 4, l15 = lane & 15;
    int wm = wid >> 1, wn = wid & 1;
    int bx = blockIdx.x, pair = blockIdx.y, b = blockIdx.z;
    int r0 = pair * 128;
    int n0 = bx * 128;

    const u16* wsrc = wb + (size_t)r0 * 256;
    const u16* xsrc = xT + ((size_t)b * N_ + n0) * 256;

    f32x4 acc[4][4];
#pragma unroll
    for (int i = 0; i < 4; i++)
#pragma unroll
        for (int j = 0; j < 4; j++) acc[i][j] = (f32x4){0.f, 0.f, 0.f, 0.f};

    int srow = lane >> 3;
    int sc8  = ((lane & 7) ^ srow) * 8;

    STAGE2(wsrc, xsrc, 256, 0, 0);
    __syncthreads();
    for (int kc = 0; kc < 4; kc++) {
        int cur = kc & 1;
        if (kc < 3) STAGE2(wsrc, xsrc, 256, kc + 1, cur ^ 1);
        const u16* Wb = &SH[cur][0];
        const u16* Xb = &SH[2 + cur][0];
#pragma unroll
        for (int ks = 0; ks < 2; ks++) {
            int cc = ks * 4 + quad;
            s16x8 af[4], bf[4];
#pragma unroll
            for (int f = 0; f < 4; f++) {
                int ar = wm * 64 + f * 16 + l15;   // A = weight side
                int br = wn * 64 + f * 16 + l15;   // B = x/n side
                af[f] = *(const s16x8*)&Wb[ar * 64 + ((cc ^ (ar & 7)) * 8)];
                bf[f] = *(const s16x8*)&Xb[br * 64 + ((cc ^ (br & 7)) * 8)];
            }
#pragma unroll
            for (int i = 0; i < 4; i++)
#pragma unroll
                for (int j = 0; j < 4; j++)
                    acc[i][j] = __builtin_amdgcn_mfma_f32_16x16x32_bf16(af[i], bf[j], acc[i][j], 0, 0, 0);
        }
        if (kc < 3) __syncthreads();
    }

    // value(mf,nf,reg): row rl = mf*16+quad*4+reg (in head), col n = wn*64+nf*16+l15
    float bA[4][4], gA[4][4], eA[4][4];
#pragma unroll
    for (int mf = 0; mf < 4; mf++)
#pragma unroll
        for (int r = 0; r < 4; r++) {
            int rl = mf * 16 + quad * 4 + r;
            bA[mf][r] = bq[r0 + wm * 64 + rl];
            gA[mf][r] = gq[rl];
            eA[mf][r] = beq[rl];
        }
#pragma unroll
    for (int mf = 0; mf < 4; mf++)
#pragma unroll
        for (int nf = 0; nf < 4; nf++)
#pragma unroll
            for (int r = 0; r < 4; r++) acc[mf][nf][r] += bA[mf][r];
#pragma unroll
    for (int nf = 0; nf < 4; nf++) {
        float s = 0.f, s2 = 0.f;
#pragma unroll
        for (int mf = 0; mf < 4; mf++)
#pragma unroll
            for (int r = 0; r < 4; r++) { float v = acc[mf][nf][r]; s += v; s2 += v * v; }
        s  += __shfl_xor(s, 16);  s  += __shfl_xor(s, 32);
        s2 += __shfl_xor(s2, 16); s2 += __shfl_xor(s2, 32);
        float mu = s * (1.f / 64.f);
        float rstd = rsqrtf(s2 * (1.f / 64.f) - mu * mu + 1e-5f);
#pragma unroll
        for (int mf = 0; mf < 4; mf++)
#pragma unroll
            for (int r = 0; r < 4; r++)
                acc[mf][nf][r] = (acc[mf][nf][r] - mu) * rstd * gA[mf][r] + eA[mf][r];
    }
    const float s_q = 0.35355339059327373f;
#pragma unroll
    for (int nf = 0; nf < 4; nf++) {
        float m = -1e30f;
#pragma unroll
        for (int mf = 0; mf < 4; mf++)
#pragma unroll
            for (int r = 0; r < 4; r++) { acc[mf][nf][r] *= s_q; m = fmaxf(m, acc[mf][nf][r]); }
        m = fmaxf(m, __shfl_xor(m, 16)); m = fmaxf(m, __shfl_xor(m, 32));
        float d = 0.f;
#pragma unroll
        for (int mf = 0; mf < 4; mf++)
#pragma unroll
            for (int r = 0; r < 4; r++) { float e = __expf(acc[mf][nf][r] - m); acc[mf][nf][r] = e; d += e; }
        d += __shfl_xor(d, 16); d += __shfl_xor(d, 32);
        float inv = 1.f / d;
#pragma unroll
        for (int mf = 0; mf < 4; mf++)
#pragma unroll
            for (int r = 0; r < 4; r++) acc[mf][nf][r] *= inv;
    }
    // store via LDS staging: region wn=0 -> SH[0] (n 0..63), wn=1 -> SH[2].
    u16* st = (wn == 0) ? &SH[0][0] : &SH[2][0];
#pragma unroll
    for (int mf = 0; mf < 4; mf++)
#pragma unroll
        for (int nf = 0; nf < 4; nf++) {
            int nl = nf * 16 + l15;
            int gl = wm * 64 + mf * 16 + quad * 4;
            int c  = gl >> 3;
            int off = nl * 128 + ((c ^ (nl & 15)) * 8) + (gl & 7);
            uint64_t w0 = (uint64_t)f2bf(acc[mf][nf][0]) | ((uint64_t)f2bf(acc[mf][nf][1]) << 16) |
                          ((uint64_t)f2bf(acc[mf][nf][2]) << 32) | ((uint64_t)f2bf(acc[mf][nf][3]) << 48);
            *(uint64_t*)&st[off] = w0;
        }
    __syncthreads();
    {
        u16* qp = qT + (size_t)b * N_ * 512;
#pragma unroll
        for (int i = 0; i < 8; i++) {
            int idx = i * 256 + tid;
            int n = idx >> 4, cp = idx & 15;
            const u16* src = (n < 64) ? &SH[0][0] : &SH[2][0];
            int nl = n & 63;
            s16x8 v = *(const s16x8*)&src[nl * 128 + ((cp ^ (nl & 15)) * 8)];
            *(s16x8*)&qp[(size_t)(n0 + n) * 512 + r0 + cp * 8] = v;
        }
    }
}

// ---------------------------------------------------------------------------
// K3: Weff[b][c][h*64+kd] = sum_vd wo[c][h*64+vd] * (ctx/rs); ctx = sum of 16
// ns-partials, layout ctxp[b][h][ns][vd][kd].
// ---------------------------------------------------------------------------
__global__ __launch_bounds__(256) void weff_kernel(
    const float* __restrict__ ctxp, const float* __restrict__ rs,
    const float* __restrict__ wo, u16* __restrict__ Weffb)
{
    __shared__ float CT[16][65];
    int tid = threadIdx.x;
    int h = blockIdx.x, b = blockIdx.y, kc = blockIdx.z;
    for (int i = tid; i < 1024; i += 256) {
        int kdl = i >> 6, vd = i & 63;
        int kd = kc * 16 + kdl;
        float s = 0.f;
#pragma unroll
        for (int sl = 0; sl < 16; sl++)
            s += ctxp[(((size_t)(b * 8 + h) * 16 + sl) * 4096) + vd * 64 + kd];
        CT[kdl][vd] = s / rs[(size_t)b * 512 + h * 64 + kd];
    }
    __syncthreads();
    int c = tid;
    float wrow[64];
    const float4* wp = (const float4*)(wo + (size_t)c * 512 + h * 64);
#pragma unroll
    for (int i = 0; i < 16; i++) { float4 t = wp[i]; wrow[i*4] = t.x; wrow[i*4+1] = t.y; wrow[i*4+2] = t.z; wrow[i*4+3] = t.w; }
    for (int kdl = 0; kdl < 16; kdl++) {
        float s = 0.f;
#pragma unroll
        for (int vd = 0; vd < 64; vd++) s += wrow[vd] * CT[kdl][vd];
        Weffb[((size_t)b * 256 + c) * 512 + h * 64 + kc * 16 + kdl] = f2bf(s);
    }
}

// ---------------------------------------------------------------------------
// K4: out[c][n] = sum_r Weff[c][r] qT[n][r] + bo[c]   (MFMA, K=512, pipelined)
// ---------------------------------------------------------------------------
__global__ __launch_bounds__(256) void out_kernel(
    const u16* __restrict__ Weffb, const u16* __restrict__ qT,
    const float* __restrict__ bo, float* __restrict__ out)
{
    __shared__ u16 SH[4][8192];
    int tid = threadIdx.x;
    int lane = tid & 63, wid = tid >> 6;
    int quad = lane >> 4, l15 = lane & 15;
    int wm = wid >> 1, wn = wid & 1;
    int n0 = blockIdx.x * 128, c0 = blockIdx.y * 128, b = blockIdx.z;
    const u16* asrc = Weffb + ((size_t)b * 256 + c0) * 512;
    const u16* bsrc = qT + ((size_t)b * N_ + n0) * 512;

    f32x4 acc[4][4];
#pragma unroll
    for (int i = 0; i < 4; i++)
#pragma unroll
        for (int j = 0; j < 4; j++) acc[i][j] = (f32x4){0.f, 0.f, 0.f, 0.f};

    int srow = lane >> 3;
    int sc8  = ((lane & 7) ^ srow) * 8;

    STAGE2(asrc, bsrc, 512, 0, 0);
    __syncthreads();
    for (int kc = 0; kc < 8; kc++) {
        int cur = kc & 1;
        if (kc < 7) STAGE2(asrc, bsrc, 512, kc + 1, cur ^ 1);
        const u16* Wb = &SH[cur][0];
        const u16* Xb = &SH[2 + cur][0];
#pragma unroll
        for (int ks = 0; ks < 2; ks++) {
            int cc = ks * 4 + quad;
            s16x8 af[4], bf[4];
#pragma unroll
            for (int f = 0; f < 4; f++) {
                int ar = wm * 64 + f * 16 + l15;
                int br = wn * 64 + f * 16 + l15;
                af[f] = *(const s16x8*)&Wb[ar * 64 + ((cc ^ (ar & 7)) * 8)];
                bf[f] = *(const s16x8*)&Xb[br * 64 + ((cc ^ (br & 7)) * 8)];
            }
#pragma unroll
            for (int i = 0; i < 4; i++)
#pragma unroll
                for (int j = 0; j < 4; j++)
                    acc[i][j] = __builtin_amdgcn_mfma_f32_16x16x32_bf16(af[i], bf[j], acc[i][j], 0, 0, 0);
        }
        if (kc < 7) __syncthreads();
    }
#pragma unroll
    for (int mf = 0; mf < 4; mf++)
#pragma unroll
        for (int r = 0; r < 4; r++) {
            int c = c0 + wm * 64 + mf * 16 + quad * 4 + r;
            float bov = bo[c];
#pragma unroll
            for (int nf = 0; nf < 4; nf++)
                out[((size_t)b * 256 + c) * N_ + n0 + wn * 64 + nf * 16 + l15] = acc[mf][nf][r] + bov;
        }
}

extern "C" void kernel_launch(void* const* d_in, const int* in_sizes, int n_in,
                              void* d_out, int out_size, void* d_ws, size_t ws_size,
                              hipStream_t stream) {
    const float* x   = (const float*)d_in[0];
    const float* wq  = (const float*)d_in[1];
    const float* bq  = (const float*)d_in[2];
    const float* wk  = (const float*)d_in[3];
    const float* bk  = (const float*)d_in[4];
    const float* wv  = (const float*)d_in[5];
    const float* bv  = (const float*)d_in[6];
    const float* wo  = (const float*)d_in[7];
    const float* bo  = (const float*)d_in[8];
    const float* gq  = (const float*)d_in[9];
    const float* beq = (const float*)d_in[10];
    const float* gk  = (const float*)d_in[11];
    const float* bek = (const float*)d_in[12];
    const float* gv  = (const float*)d_in[13];
    const float* bev = (const float*)d_in[14];
    float* out = (float*)d_out;

    char* ws = (char*)d_ws;
    // xT   [0, 33554432)            bf16 [B][N][C]
    // wb   [33554432, 34340864)     bf16 [3][512][256]
    // qT   [34340864, 101449728)    bf16 [B][N][512]
    // ctxp [101449728, 109838336)   fp32 [B][8][16][64][64]  (16 ns-partials)
    // rs   [169082880, 169091072)   fp32 [B][512]
    // Weff [169091072, 170139648)   bf16 [B][256][512]
    u16* xT      = (u16*)(ws);
    u16* wb      = (u16*)(ws + 33554432ULL);
    u16* qT      = (u16*)(ws + 34340864ULL);
    float* ctxp  = (float*)(ws + 101449728ULL);
    float* rs    = (float*)(ws + 169082880ULL);
    u16* Weffb   = (u16*)(ws + 169091072ULL);

    cvtw_kernel<<<dim3(512, 3), 256, 0, stream>>>(wq, wk, wv, wb);
    transpose_kernel<<<dim3(256, 4, 4), 256, 0, stream>>>(x, xT);
    zero_kernel<<<dim3(8), 256, 0, stream>>>(rs, 2048);

    kvctx_kernel<<<dim3(16, 8, 4), 256, 0, stream>>>(
        xT, wb, bk, bv, gk, bek, gv, bev, ctxp, rs);

    q_kernel<<<dim3(128, 4, 4), 256, 0, stream>>>(xT, wb, bq, gq, beq, qT);

    weff_kernel<<<dim3(8, 4, 4), 256, 0, stream>>>(ctxp, rs, wo, Weffb);

    out_kernel<<<dim3(128, 2, 4), 256, 0, stream>>>(Weffb, qT, bo, out);
}